// Round 3
// baseline (356.048 us; speedup 1.0000x reference)
//
#include <hip/hip_runtime.h>
#include <math.h>

#define N_NODES 100000
#define N_EDGES 1600000
#define F0 32
#define F1 16
#define F2 8
#define NCLS 6
#define NGRAPH 64

#define NB   256      // buckets (== one block per bucket in gin kernels)
#define GSZ  391      // nodes per bucket: ceil(100000/256); 256*391 = 100096
#define GP   392      // padded stride for LDS agg
#define EPC  6250     // edges per chunk: N_EDGES / NB exactly

// exact floor(d/391) for d < 2^17 via magic multiply (2^37/391 rounded up)
__device__ __forceinline__ int bucket_of(unsigned d) {
    return (int)(__umulhi(d, 351531851u) >> 5);
}

// ---- xw1 = x @ W1a  (project 32->16 BEFORE aggregation; linearity) ----
__global__ __launch_bounds__(256) void xform_k(
    const float* __restrict__ x, const float* __restrict__ W1a,
    float* __restrict__ xw1) {
    __shared__ float sW[F0 * F1];
    int t = threadIdx.x;
    for (int i = t; i < F0 * F1; i += blockDim.x) sW[i] = W1a[i];
    __syncthreads();
    int n = blockIdx.x * blockDim.x + t;
    if (n >= N_NODES) return;
    const float4* xp = reinterpret_cast<const float4*>(x) + n * (F0 / 4);
    float xi[F0];
#pragma unroll
    for (int q = 0; q < F0 / 4; q++) {
        float4 v = xp[q];
        xi[4 * q + 0] = v.x; xi[4 * q + 1] = v.y;
        xi[4 * q + 2] = v.z; xi[4 * q + 3] = v.w;
    }
    float o[F1];
#pragma unroll
    for (int j = 0; j < F1; j++) {
        float s = 0.0f;
#pragma unroll
        for (int k = 0; k < F0; k++) s += xi[k] * sW[k * F1 + j];
        o[j] = s;
    }
    float4* op = reinterpret_cast<float4*>(xw1) + n * (F1 / 4);
#pragma unroll
    for (int q = 0; q < F1 / 4; q++)
        op[q] = make_float4(o[4 * q + 0], o[4 * q + 1], o[4 * q + 2], o[4 * q + 3]);
}

// ---- bucket histogram: LDS per chunk, one global atomic per (chunk,bucket) ----
__global__ __launch_bounds__(256) void bhist_k(
    const int* __restrict__ ei, int* __restrict__ bhist) {
    __shared__ int hist[NB];
    int t = threadIdx.x, c = blockIdx.x;
    hist[t] = 0;
    __syncthreads();
    int base = c * EPC;
    for (int i = t; i < EPC; i += 256) {
        int d = ei[N_EDGES + base + i];
        atomicAdd(&hist[bucket_of((unsigned)d)], 1);
    }
    __syncthreads();
    if (hist[t]) atomicAdd(&bhist[t], hist[t]);
}

// ---- scan 256 bucket totals -> bbase[257] (exclusive) and gcursor init ----
__global__ __launch_bounds__(256) void bscan_k(
    const int* __restrict__ bhist, int* __restrict__ bbase,
    int* __restrict__ gcursor) {
    __shared__ int sc[NB];
    int t = threadIdx.x;
    int own = bhist[t];
    sc[t] = own;
    __syncthreads();
    for (int off = 1; off < NB; off <<= 1) {
        int v = sc[t];
        if (t >= off) v += sc[t - off];
        __syncthreads();
        sc[t] = v;
        __syncthreads();
    }
    bbase[t + 1] = sc[t];            // inclusive
    if (t == 0) bbase[0] = 0;
    gcursor[t] = sc[t] - own;        // exclusive start = append cursor
}

// ---- partition: pack (dstLocal<<17 | src) into bucket-contiguous pairs ----
__global__ __launch_bounds__(256) void passA_k(
    const int* __restrict__ ei, int* __restrict__ gcursor,
    int* __restrict__ pairs) {
    __shared__ int hist[NB];
    __shared__ int cur[NB];
    int t = threadIdx.x, c = blockIdx.x;
    hist[t] = 0;
    __syncthreads();
    int base = c * EPC;
    for (int i = t; i < EPC; i += 256) {
        int d = ei[N_EDGES + base + i];
        atomicAdd(&hist[bucket_of((unsigned)d)], 1);
    }
    __syncthreads();
    // reserve a contiguous sub-range of each bucket for this chunk
    cur[t] = hist[t] ? atomicAdd(&gcursor[t], hist[t]) : 0;
    __syncthreads();
    for (int i = t; i < EPC; i += 256) {
        int e = base + i;
        int s = ei[e];
        int d = ei[N_EDGES + e];
        int b = bucket_of((unsigned)d);
        int dl = d - b * GSZ;
        int pos = atomicAdd(&cur[b], 1);          // LDS cursor
        pairs[pos] = (dl << 17) | s;
    }
}

// ---- layer 1: bucket-local LDS scatter-agg + fused MLP1 + W2a projection ----
__global__ __launch_bounds__(1024) void gin1B_k(
    const float* __restrict__ xw1, const int* __restrict__ pairs,
    const int* __restrict__ bbase, const float* __restrict__ b1a,
    const float* __restrict__ W1b, const float* __restrict__ b1b,
    const float* __restrict__ W2a, float* __restrict__ h1w) {
    __shared__ float agg[F1 * GP];            // agg[k][dstLocal], padded
    __shared__ float sW1b[F1 * F1];
    __shared__ float sW2a[F1 * F2];
    __shared__ float sb1a[F1];
    __shared__ float sb1b[F1];
    int t = threadIdx.x, b = blockIdx.x;
    for (int i = t; i < F1 * GP; i += 1024) agg[i] = 0.0f;
    if (t < F1 * F1) sW1b[t] = W1b[t];
    if (t < F1 * F2) sW2a[t] = W2a[t];
    if (t < F1) { sb1a[t] = b1a[t]; sb1b[t] = b1b[t]; }
    __syncthreads();

    int e0 = bbase[b], e1 = bbase[b + 1];
    const float4* X = reinterpret_cast<const float4*>(xw1);
    for (int i = e0 + t; i < e1; i += 1024) {
        int p = pairs[i];
        int src = p & 0x1FFFF;
        int dl = p >> 17;
        const float4* xp = X + src * 4;
        float4 q0 = xp[0], q1 = xp[1], q2 = xp[2], q3 = xp[3];
        float q[F1] = {q0.x, q0.y, q0.z, q0.w, q1.x, q1.y, q1.z, q1.w,
                       q2.x, q2.y, q2.z, q2.w, q3.x, q3.y, q3.z, q3.w};
#pragma unroll
        for (int k = 0; k < F1; k++) atomicAdd(&agg[k * GP + dl], q[k]);
    }
    __syncthreads();

    if (t < GSZ) {
        int n = b * GSZ + t;
        if (n < N_NODES) {
            const float4* xs = X + n * 4;
            float4 r0 = xs[0], r1 = xs[1], r2 = xs[2], r3 = xs[3];
            float self[F1] = {r0.x, r0.y, r0.z, r0.w, r1.x, r1.y, r1.z, r1.w,
                              r2.x, r2.y, r2.z, r2.w, r3.x, r3.y, r3.z, r3.w};
            float u[F1];
#pragma unroll
            for (int k = 0; k < F1; k++)
                u[k] = fmaxf(agg[k * GP + t] + self[k] + sb1a[k], 0.0f);
            float h[F1];
#pragma unroll
            for (int j = 0; j < F1; j++) {
                float s = sb1b[j];
#pragma unroll
                for (int k = 0; k < F1; k++) s += u[k] * sW1b[k * F1 + j];
                h[j] = fmaxf(s, 0.0f);        // relu∘relu = relu
            }
            float o[F2];
#pragma unroll
            for (int j = 0; j < F2; j++) {
                float s = 0.0f;
#pragma unroll
                for (int k = 0; k < F1; k++) s += h[k] * sW2a[k * F2 + j];
                o[j] = s;
            }
            float4* hp = reinterpret_cast<float4*>(h1w) + n * 2;
            hp[0] = make_float4(o[0], o[1], o[2], o[3]);
            hp[1] = make_float4(o[4], o[5], o[6], o[7]);
        }
    }
}

// ---- layer 2: bucket-local scatter-agg + MLP2 + fused mean-pool ----
__global__ __launch_bounds__(1024) void gin2B_k(
    const float* __restrict__ h1w, const int* __restrict__ pairs,
    const int* __restrict__ bbase, const float* __restrict__ b2a,
    const float* __restrict__ W2b, const float* __restrict__ b2b,
    const int* __restrict__ batch, float* __restrict__ gsum,
    float* __restrict__ gcnt) {
    __shared__ float agg[F2 * GP];
    __shared__ float sW2b[F2 * F2];
    __shared__ float sb2a[F2];
    __shared__ float sb2b[F2];
    __shared__ float ls[NGRAPH * F2];
    __shared__ float lc[NGRAPH];
    int t = threadIdx.x, b = blockIdx.x;
    for (int i = t; i < F2 * GP; i += 1024) agg[i] = 0.0f;
    if (t < F2 * F2) sW2b[t] = W2b[t];
    if (t < F2) { sb2a[t] = b2a[t]; sb2b[t] = b2b[t]; }
    if (t < NGRAPH * F2) ls[t] = 0.0f;
    if (t < NGRAPH) lc[t] = 0.0f;
    __syncthreads();

    int e0 = bbase[b], e1 = bbase[b + 1];
    const float4* H = reinterpret_cast<const float4*>(h1w);
    for (int i = e0 + t; i < e1; i += 1024) {
        int p = pairs[i];
        int src = p & 0x1FFFF;
        int dl = p >> 17;
        const float4* hp = H + src * 2;
        float4 q0 = hp[0], q1 = hp[1];
        float q[F2] = {q0.x, q0.y, q0.z, q0.w, q1.x, q1.y, q1.z, q1.w};
#pragma unroll
        for (int k = 0; k < F2; k++) atomicAdd(&agg[k * GP + dl], q[k]);
    }
    __syncthreads();

    if (t < GSZ) {
        int n = b * GSZ + t;
        if (n < N_NODES) {
            const float4* hs = H + n * 2;
            float4 r0 = hs[0], r1 = hs[1];
            float self[F2] = {r0.x, r0.y, r0.z, r0.w, r1.x, r1.y, r1.z, r1.w};
            float u[F2];
#pragma unroll
            for (int k = 0; k < F2; k++)
                u[k] = fmaxf(agg[k * GP + t] + self[k] + sb2a[k], 0.0f);
            float v[F2];
#pragma unroll
            for (int j = 0; j < F2; j++) {
                float s = sb2b[j];
#pragma unroll
                for (int k = 0; k < F2; k++) s += u[k] * sW2b[k * F2 + j];
                v[j] = fmaxf(s, 0.0f);
            }
            int g = batch[n];
#pragma unroll
            for (int j = 0; j < F2; j++) atomicAdd(&ls[g * F2 + j], v[j]);
            atomicAdd(&lc[g], 1.0f);
        }
    }
    __syncthreads();
    if (t < NGRAPH * F2 && ls[t] != 0.0f) atomicAdd(&gsum[t], ls[t]);
    if (t < NGRAPH && lc[t] != 0.0f) atomicAdd(&gcnt[t], lc[t]);
}

// ---------------- final: pooled -> FC -> log_softmax ----------------
__global__ void final_k(const float* __restrict__ gsum,
                        const float* __restrict__ gcnt,
                        const float* __restrict__ Wfc, const float* __restrict__ bfc,
                        float* __restrict__ out) {
    int g = threadIdx.x;
    if (g >= NGRAPH) return;
    float cnt = fmaxf(gcnt[g], 1.0f);
    float p[F2];
#pragma unroll
    for (int f = 0; f < F2; f++) p[f] = gsum[g * F2 + f] / cnt;
    float l[NCLS];
#pragma unroll
    for (int c = 0; c < NCLS; c++) {
        float s = bfc[c];
#pragma unroll
        for (int f = 0; f < F2; f++) s += p[f] * Wfc[f * NCLS + c];
        l[c] = s;
    }
    float m = -INFINITY;
#pragma unroll
    for (int c = 0; c < NCLS; c++) m = fmaxf(m, l[c]);
    float s = 0.0f;
#pragma unroll
    for (int c = 0; c < NCLS; c++) s += expf(l[c] - m);
    float lse = m + logf(s);
#pragma unroll
    for (int c = 0; c < NCLS; c++) out[g * NCLS + c] = l[c] - lse;
}

extern "C" void kernel_launch(void* const* d_in, const int* in_sizes, int n_in,
                              void* d_out, int out_size, void* d_ws, size_t ws_size,
                              hipStream_t stream) {
    const float* x    = (const float*)d_in[0];
    const int*   ei   = (const int*)d_in[1];   // [2, N_EDGES]
    const int*   batch= (const int*)d_in[2];   // [N_NODES], sorted
    const float* W1a  = (const float*)d_in[3];
    const float* b1a  = (const float*)d_in[4];
    const float* W1b  = (const float*)d_in[5];
    const float* b1b  = (const float*)d_in[6];
    const float* W2a  = (const float*)d_in[7];
    const float* b2a  = (const float*)d_in[8];
    const float* W2b  = (const float*)d_in[9];
    const float* b2b  = (const float*)d_in[10];
    const float* Wfc  = (const float*)d_in[11];
    const float* bfc  = (const float*)d_in[12];
    float* out = (float*)d_out;

    // workspace layout (4-byte units), ~16 MB total
    float* ws      = (float*)d_ws;
    float* xw1     = ws;                                   // N_NODES*16 (16B aligned)
    float* h1w     = xw1 + (size_t)N_NODES * F1;           // N_NODES*8
    int*   pairs   = (int*)(h1w + (size_t)N_NODES * F2);   // N_EDGES
    int*   bbase   = pairs + N_EDGES;                      // NB+1
    int*   gcursor = bbase + (NB + 1);                     // NB
    int*   bhist   = gcursor + NB;                         // NB      (memset)
    float* gsum    = (float*)(bhist + NB);                 // NGRAPH*F2 (memset)
    float* gcnt    = gsum + NGRAPH * F2;                   // NGRAPH  (memset)

    // one memset: bhist + gsum + gcnt adjacent
    hipMemsetAsync(bhist, 0, (NB + NGRAPH * F2 + NGRAPH) * sizeof(int), stream);

    xform_k<<<(N_NODES + 255) / 256, 256, 0, stream>>>(x, W1a, xw1);
    bhist_k<<<NB, 256, 0, stream>>>(ei, bhist);
    bscan_k<<<1, 256, 0, stream>>>(bhist, bbase, gcursor);
    passA_k<<<NB, 256, 0, stream>>>(ei, gcursor, pairs);
    gin1B_k<<<NB, 1024, 0, stream>>>(xw1, pairs, bbase, b1a, W1b, b1b, W2a, h1w);
    gin2B_k<<<NB, 1024, 0, stream>>>(h1w, pairs, bbase, b2a, W2b, b2b,
                                     batch, gsum, gcnt);
    final_k<<<1, 64, 0, stream>>>(gsum, gcnt, Wfc, bfc, out);
}

// Round 4
// 353.178 us; speedup vs baseline: 1.0081x; 1.0081x over previous
//
#include <hip/hip_runtime.h>
#include <math.h>

#define N_NODES 100000
#define N_EDGES 1600000
#define F0 32
#define F1 16
#define F2 8
#define NCLS 6
#define NGRAPH 64

#define NB   256      // buckets (== one block per bucket in gin kernels)
#define GSZ  391      // nodes per bucket: ceil(100000/256); 256*391 = 100096
#define EPC  6250     // edges per chunk: N_EDGES / NB exactly
#define ST1  17       // LDS stride (floats) per node, layer 1 (odd -> bank spread)
#define ST2  9        // LDS stride per node, layer 2

// exact floor(d/391) for d < 2^17 via magic multiply (2^37/391 rounded up)
__device__ __forceinline__ int bucket_of(unsigned d) {
    return (int)(__umulhi(d, 351531851u) >> 5);
}

// ---- xw1 = x @ W1a  (project 32->16 BEFORE aggregation; linearity) ----
__global__ __launch_bounds__(256) void xform_k(
    const float* __restrict__ x, const float* __restrict__ W1a,
    float* __restrict__ xw1) {
    __shared__ float sW[F0 * F1];
    int t = threadIdx.x;
    for (int i = t; i < F0 * F1; i += blockDim.x) sW[i] = W1a[i];
    __syncthreads();
    int n = blockIdx.x * blockDim.x + t;
    if (n >= N_NODES) return;
    const float4* xp = reinterpret_cast<const float4*>(x) + n * (F0 / 4);
    float xi[F0];
#pragma unroll
    for (int q = 0; q < F0 / 4; q++) {
        float4 v = xp[q];
        xi[4 * q + 0] = v.x; xi[4 * q + 1] = v.y;
        xi[4 * q + 2] = v.z; xi[4 * q + 3] = v.w;
    }
    float o[F1];
#pragma unroll
    for (int j = 0; j < F1; j++) {
        float s = 0.0f;
#pragma unroll
        for (int k = 0; k < F0; k++) s += xi[k] * sW[k * F1 + j];
        o[j] = s;
    }
    float4* op = reinterpret_cast<float4*>(xw1) + n * (F1 / 4);
#pragma unroll
    for (int q = 0; q < F1 / 4; q++)
        op[q] = make_float4(o[4 * q + 0], o[4 * q + 1], o[4 * q + 2], o[4 * q + 3]);
}

// ---- bucket histogram: LDS per chunk, one global atomic per (chunk,bucket) ----
__global__ __launch_bounds__(256) void bhist_k(
    const int* __restrict__ ei, int* __restrict__ bhist) {
    __shared__ int hist[NB];
    int t = threadIdx.x, c = blockIdx.x;
    hist[t] = 0;
    __syncthreads();
    int base = c * EPC;
    for (int i = t; i < EPC; i += 256) {
        int d = ei[N_EDGES + base + i];
        atomicAdd(&hist[bucket_of((unsigned)d)], 1);
    }
    __syncthreads();
    if (hist[t]) atomicAdd(&bhist[t], hist[t]);
}

// ---- scan 256 bucket totals -> bbase[257] (exclusive) and gcursor init ----
__global__ __launch_bounds__(256) void bscan_k(
    const int* __restrict__ bhist, int* __restrict__ bbase,
    int* __restrict__ gcursor) {
    __shared__ int sc[NB];
    int t = threadIdx.x;
    int own = bhist[t];
    sc[t] = own;
    __syncthreads();
    for (int off = 1; off < NB; off <<= 1) {
        int v = sc[t];
        if (t >= off) v += sc[t - off];
        __syncthreads();
        sc[t] = v;
        __syncthreads();
    }
    bbase[t + 1] = sc[t];            // inclusive
    if (t == 0) bbase[0] = 0;
    gcursor[t] = sc[t] - own;        // exclusive start = append cursor
}

// ---- partition: pack (dstLocal<<17 | src) into bucket-contiguous pairs ----
__global__ __launch_bounds__(256) void passA_k(
    const int* __restrict__ ei, int* __restrict__ gcursor,
    int* __restrict__ pairs) {
    __shared__ int hist[NB];
    __shared__ int cur[NB];
    int t = threadIdx.x, c = blockIdx.x;
    hist[t] = 0;
    __syncthreads();
    int base = c * EPC;
    for (int i = t; i < EPC; i += 256) {
        int d = ei[N_EDGES + base + i];
        atomicAdd(&hist[bucket_of((unsigned)d)], 1);
    }
    __syncthreads();
    // reserve a contiguous sub-range of each bucket for this chunk
    cur[t] = hist[t] ? atomicAdd(&gcursor[t], hist[t]) : 0;
    __syncthreads();
    for (int i = t; i < EPC; i += 256) {
        int e = base + i;
        int s = ei[e];
        int d = ei[N_EDGES + e];
        int b = bucket_of((unsigned)d);
        int dl = d - b * GSZ;
        int pos = atomicAdd(&cur[b], 1);          // LDS cursor
        pairs[pos] = (dl << 17) | s;
    }
}

// ---- layer 1: 4 lanes per edge -> one coalesced 64B line request/edge ----
__global__ __launch_bounds__(1024) void gin1B_k(
    const float* __restrict__ xw1, const int* __restrict__ pairs,
    const int* __restrict__ bbase, const float* __restrict__ b1a,
    const float* __restrict__ W1b, const float* __restrict__ b1b,
    const float* __restrict__ W2a, float* __restrict__ h1w) {
    __shared__ float agg[GSZ * ST1];          // agg[dl][f], stride 17
    __shared__ float sW1b[F1 * F1];
    __shared__ float sW2a[F1 * F2];
    __shared__ float sb1a[F1];
    __shared__ float sb1b[F1];
    int t = threadIdx.x, b = blockIdx.x;
    for (int i = t; i < GSZ * ST1; i += 1024) agg[i] = 0.0f;
    if (t < F1 * F1) sW1b[t] = W1b[t];
    if (t < F1 * F2) sW2a[t] = W2a[t];
    if (t < F1) { sb1a[t] = b1a[t]; sb1b[t] = b1b[t]; }
    __syncthreads();

    int e0 = bbase[b], e1 = bbase[b + 1];
    const float4* X = reinterpret_cast<const float4*>(xw1);
    int qs = t & 3;                // sub-lane: which float4 of the row
    int f0 = qs * 4;               // features this lane accumulates
    const int QPB = 1024 / 4;      // edges per block per iteration
    int i = e0 + (t >> 2);
    for (; i + QPB < e1; i += 2 * QPB) {   // unroll x2 for 2 gathers in flight
        int p0 = pairs[i];
        int p1 = pairs[i + QPB];
        float4 a = X[(p0 & 0x1FFFF) * 4 + qs];
        float4 c = X[(p1 & 0x1FFFF) * 4 + qs];
        float* A0 = &agg[(p0 >> 17) * ST1 + f0];
        atomicAdd(&A0[0], a.x); atomicAdd(&A0[1], a.y);
        atomicAdd(&A0[2], a.z); atomicAdd(&A0[3], a.w);
        float* A1 = &agg[(p1 >> 17) * ST1 + f0];
        atomicAdd(&A1[0], c.x); atomicAdd(&A1[1], c.y);
        atomicAdd(&A1[2], c.z); atomicAdd(&A1[3], c.w);
    }
    if (i < e1) {
        int p0 = pairs[i];
        float4 a = X[(p0 & 0x1FFFF) * 4 + qs];
        float* A0 = &agg[(p0 >> 17) * ST1 + f0];
        atomicAdd(&A0[0], a.x); atomicAdd(&A0[1], a.y);
        atomicAdd(&A0[2], a.z); atomicAdd(&A0[3], a.w);
    }
    __syncthreads();

    if (t < GSZ) {
        int n = b * GSZ + t;
        if (n < N_NODES) {
            const float4* xs = X + n * 4;
            float4 r0 = xs[0], r1 = xs[1], r2 = xs[2], r3 = xs[3];
            float self[F1] = {r0.x, r0.y, r0.z, r0.w, r1.x, r1.y, r1.z, r1.w,
                              r2.x, r2.y, r2.z, r2.w, r3.x, r3.y, r3.z, r3.w};
            float u[F1];
#pragma unroll
            for (int k = 0; k < F1; k++)
                u[k] = fmaxf(agg[t * ST1 + k] + self[k] + sb1a[k], 0.0f);
            float h[F1];
#pragma unroll
            for (int j = 0; j < F1; j++) {
                float s = sb1b[j];
#pragma unroll
                for (int k = 0; k < F1; k++) s += u[k] * sW1b[k * F1 + j];
                h[j] = fmaxf(s, 0.0f);        // relu∘relu = relu
            }
            float o[F2];
#pragma unroll
            for (int j = 0; j < F2; j++) {
                float s = 0.0f;
#pragma unroll
                for (int k = 0; k < F1; k++) s += h[k] * sW2a[k * F2 + j];
                o[j] = s;
            }
            float4* hp = reinterpret_cast<float4*>(h1w) + n * 2;
            hp[0] = make_float4(o[0], o[1], o[2], o[3]);
            hp[1] = make_float4(o[4], o[5], o[6], o[7]);
        }
    }
}

// ---- layer 2: 2 lanes per edge -> one coalesced 32B request/edge ----
__global__ __launch_bounds__(1024) void gin2B_k(
    const float* __restrict__ h1w, const int* __restrict__ pairs,
    const int* __restrict__ bbase, const float* __restrict__ b2a,
    const float* __restrict__ W2b, const float* __restrict__ b2b,
    const int* __restrict__ batch, float* __restrict__ gsum,
    float* __restrict__ gcnt) {
    __shared__ float agg[GSZ * ST2];          // agg[dl][f], stride 9
    __shared__ float sW2b[F2 * F2];
    __shared__ float sb2a[F2];
    __shared__ float sb2b[F2];
    __shared__ float ls[NGRAPH * F2];
    __shared__ float lc[NGRAPH];
    int t = threadIdx.x, b = blockIdx.x;
    for (int i = t; i < GSZ * ST2; i += 1024) agg[i] = 0.0f;
    if (t < F2 * F2) sW2b[t] = W2b[t];
    if (t < F2) { sb2a[t] = b2a[t]; sb2b[t] = b2b[t]; }
    if (t < NGRAPH * F2) ls[t] = 0.0f;
    if (t < NGRAPH) lc[t] = 0.0f;
    __syncthreads();

    int e0 = bbase[b], e1 = bbase[b + 1];
    const float4* H = reinterpret_cast<const float4*>(h1w);
    int hs = t & 1;
    int f0 = hs * 4;
    const int PPB = 1024 / 2;
    int i = e0 + (t >> 1);
    for (; i + PPB < e1; i += 2 * PPB) {
        int p0 = pairs[i];
        int p1 = pairs[i + PPB];
        float4 a = H[(p0 & 0x1FFFF) * 2 + hs];
        float4 c = H[(p1 & 0x1FFFF) * 2 + hs];
        float* A0 = &agg[(p0 >> 17) * ST2 + f0];
        atomicAdd(&A0[0], a.x); atomicAdd(&A0[1], a.y);
        atomicAdd(&A0[2], a.z); atomicAdd(&A0[3], a.w);
        float* A1 = &agg[(p1 >> 17) * ST2 + f0];
        atomicAdd(&A1[0], c.x); atomicAdd(&A1[1], c.y);
        atomicAdd(&A1[2], c.z); atomicAdd(&A1[3], c.w);
    }
    if (i < e1) {
        int p0 = pairs[i];
        float4 a = H[(p0 & 0x1FFFF) * 2 + hs];
        float* A0 = &agg[(p0 >> 17) * ST2 + f0];
        atomicAdd(&A0[0], a.x); atomicAdd(&A0[1], a.y);
        atomicAdd(&A0[2], a.z); atomicAdd(&A0[3], a.w);
    }
    __syncthreads();

    if (t < GSZ) {
        int n = b * GSZ + t;
        if (n < N_NODES) {
            const float4* hsrow = H + n * 2;
            float4 r0 = hsrow[0], r1 = hsrow[1];
            float self[F2] = {r0.x, r0.y, r0.z, r0.w, r1.x, r1.y, r1.z, r1.w};
            float u[F2];
#pragma unroll
            for (int k = 0; k < F2; k++)
                u[k] = fmaxf(agg[t * ST2 + k] + self[k] + sb2a[k], 0.0f);
            float v[F2];
#pragma unroll
            for (int j = 0; j < F2; j++) {
                float s = sb2b[j];
#pragma unroll
                for (int k = 0; k < F2; k++) s += u[k] * sW2b[k * F2 + j];
                v[j] = fmaxf(s, 0.0f);
            }
            int g = batch[n];
#pragma unroll
            for (int j = 0; j < F2; j++) atomicAdd(&ls[g * F2 + j], v[j]);
            atomicAdd(&lc[g], 1.0f);
        }
    }
    __syncthreads();
    if (t < NGRAPH * F2 && ls[t] != 0.0f) atomicAdd(&gsum[t], ls[t]);
    if (t < NGRAPH && lc[t] != 0.0f) atomicAdd(&gcnt[t], lc[t]);
}

// ---------------- final: pooled -> FC -> log_softmax ----------------
__global__ void final_k(const float* __restrict__ gsum,
                        const float* __restrict__ gcnt,
                        const float* __restrict__ Wfc, const float* __restrict__ bfc,
                        float* __restrict__ out) {
    int g = threadIdx.x;
    if (g >= NGRAPH) return;
    float cnt = fmaxf(gcnt[g], 1.0f);
    float p[F2];
#pragma unroll
    for (int f = 0; f < F2; f++) p[f] = gsum[g * F2 + f] / cnt;
    float l[NCLS];
#pragma unroll
    for (int c = 0; c < NCLS; c++) {
        float s = bfc[c];
#pragma unroll
        for (int f = 0; f < F2; f++) s += p[f] * Wfc[f * NCLS + c];
        l[c] = s;
    }
    float m = -INFINITY;
#pragma unroll
    for (int c = 0; c < NCLS; c++) m = fmaxf(m, l[c]);
    float s = 0.0f;
#pragma unroll
    for (int c = 0; c < NCLS; c++) s += expf(l[c] - m);
    float lse = m + logf(s);
#pragma unroll
    for (int c = 0; c < NCLS; c++) out[g * NCLS + c] = l[c] - lse;
}

extern "C" void kernel_launch(void* const* d_in, const int* in_sizes, int n_in,
                              void* d_out, int out_size, void* d_ws, size_t ws_size,
                              hipStream_t stream) {
    const float* x    = (const float*)d_in[0];
    const int*   ei   = (const int*)d_in[1];   // [2, N_EDGES]
    const int*   batch= (const int*)d_in[2];   // [N_NODES], sorted
    const float* W1a  = (const float*)d_in[3];
    const float* b1a  = (const float*)d_in[4];
    const float* W1b  = (const float*)d_in[5];
    const float* b1b  = (const float*)d_in[6];
    const float* W2a  = (const float*)d_in[7];
    const float* b2a  = (const float*)d_in[8];
    const float* W2b  = (const float*)d_in[9];
    const float* b2b  = (const float*)d_in[10];
    const float* Wfc  = (const float*)d_in[11];
    const float* bfc  = (const float*)d_in[12];
    float* out = (float*)d_out;

    // workspace layout (4-byte units), ~16 MB total
    float* ws      = (float*)d_ws;
    float* xw1     = ws;                                   // N_NODES*16 (16B aligned)
    float* h1w     = xw1 + (size_t)N_NODES * F1;           // N_NODES*8
    int*   pairs   = (int*)(h1w + (size_t)N_NODES * F2);   // N_EDGES
    int*   bbase   = pairs + N_EDGES;                      // NB+1
    int*   gcursor = bbase + (NB + 1);                     // NB
    int*   bhist   = gcursor + NB;                         // NB      (memset)
    float* gsum    = (float*)(bhist + NB);                 // NGRAPH*F2 (memset)
    float* gcnt    = gsum + NGRAPH * F2;                   // NGRAPH  (memset)

    // one memset: bhist + gsum + gcnt adjacent
    hipMemsetAsync(bhist, 0, (NB + NGRAPH * F2 + NGRAPH) * sizeof(int), stream);

    xform_k<<<(N_NODES + 255) / 256, 256, 0, stream>>>(x, W1a, xw1);
    bhist_k<<<NB, 256, 0, stream>>>(ei, bhist);
    bscan_k<<<1, 256, 0, stream>>>(bhist, bbase, gcursor);
    passA_k<<<NB, 256, 0, stream>>>(ei, gcursor, pairs);
    gin1B_k<<<NB, 1024, 0, stream>>>(xw1, pairs, bbase, b1a, W1b, b1b, W2a, h1w);
    gin2B_k<<<NB, 1024, 0, stream>>>(h1w, pairs, bbase, b2a, W2b, b2b,
                                     batch, gsum, gcnt);
    final_k<<<1, 64, 0, stream>>>(gsum, gcnt, Wfc, bfc, out);
}

// Round 6
// 201.725 us; speedup vs baseline: 1.7650x; 1.7508x over previous
//
#include <hip/hip_runtime.h>
#include <math.h>

#define N_NODES 100000
#define N_EDGES 1600000
#define F0 32
#define F1 16
#define F2 8
#define NCLS 6
#define NGRAPH 64

#define NB   196       // buckets of 512 nodes: ceil(100000/512)
#define BSH  9         // bucket shift (512 nodes/bucket, power of 2 -> exact)
#define GSZ  512       // nodes per bucket
#define NCH  256       // histogram chunks
#define EPC  6250      // edges per chunk: N_EDGES / NCH exactly
#define PB   512       // passB / scan width

// ---- xw1 = x @ W1a  (project 32->16 BEFORE aggregation; linearity) ----
__global__ __launch_bounds__(256) void xform_k(
    const float* __restrict__ x, const float* __restrict__ W1a,
    float* __restrict__ xw1) {
    __shared__ float sW[F0 * F1];
    int t = threadIdx.x;
    for (int i = t; i < F0 * F1; i += blockDim.x) sW[i] = W1a[i];
    __syncthreads();
    int n = blockIdx.x * blockDim.x + t;
    if (n >= N_NODES) return;
    const float4* xp = reinterpret_cast<const float4*>(x) + n * (F0 / 4);
    float xi[F0];
#pragma unroll
    for (int q = 0; q < F0 / 4; q++) {
        float4 v = xp[q];
        xi[4 * q + 0] = v.x; xi[4 * q + 1] = v.y;
        xi[4 * q + 2] = v.z; xi[4 * q + 3] = v.w;
    }
    float o[F1];
#pragma unroll
    for (int j = 0; j < F1; j++) {
        float s = 0.0f;
#pragma unroll
        for (int k = 0; k < F0; k++) s += xi[k] * sW[k * F1 + j];
        o[j] = s;
    }
    float4* op = reinterpret_cast<float4*>(xw1) + n * (F1 / 4);
#pragma unroll
    for (int q = 0; q < F1 / 4; q++)
        op[q] = make_float4(o[4 * q + 0], o[4 * q + 1], o[4 * q + 2], o[4 * q + 3]);
}

// ---- bucket histogram: LDS per chunk, one global atomic per (chunk,bucket) ----
__global__ __launch_bounds__(256) void bhist_k(
    const int* __restrict__ ei, int* __restrict__ bhist) {
    __shared__ int hist[256];
    int t = threadIdx.x, c = blockIdx.x;
    hist[t] = 0;
    __syncthreads();
    int base = c * EPC;
    for (int i = t; i < EPC; i += 256)
        atomicAdd(&hist[ei[N_EDGES + base + i] >> BSH], 1);
    __syncthreads();
    if (t < NB && hist[t]) atomicAdd(&bhist[t], hist[t]);
}

// ---- scan 196 bucket totals -> bbase (exclusive) and gcursor init ----
__global__ __launch_bounds__(256) void bscan_k(
    const int* __restrict__ bhist, int* __restrict__ bbase,
    int* __restrict__ gcursor) {
    __shared__ int sc[256];
    int t = threadIdx.x;
    int own = (t < NB) ? bhist[t] : 0;
    sc[t] = own;
    __syncthreads();
    for (int off = 1; off < 256; off <<= 1) {
        int v = sc[t];
        if (t >= off) v += sc[t - off];
        __syncthreads();
        sc[t] = v;
        __syncthreads();
    }
    bbase[t + 1] = sc[t];            // inclusive
    if (t == 0) bbase[0] = 0;
    gcursor[t] = sc[t] - own;        // exclusive start = append cursor
}

// ---- passA: partition edges into 196 dst-buckets; pack (dl<<17 | src) ----
__global__ __launch_bounds__(256) void passA_k(
    const int* __restrict__ ei, int* __restrict__ gcursor,
    int* __restrict__ pairs) {
    __shared__ int hist[256];
    __shared__ int cur[256];
    __shared__ int sdst[EPC];        // stage dst: read global once
    int t = threadIdx.x, c = blockIdx.x;
    hist[t] = 0;
    __syncthreads();
    int base = c * EPC;
    for (int i = t; i < EPC; i += 256) {
        int d = ei[N_EDGES + base + i];
        sdst[i] = d;
        atomicAdd(&hist[d >> BSH], 1);
    }
    __syncthreads();
    // reserve a contiguous sub-range of each bucket for this chunk
    cur[t] = hist[t] ? atomicAdd(&gcursor[t], hist[t]) : 0;
    __syncthreads();
    for (int i = t; i < EPC; i += 256) {
        int s = ei[base + i];
        int d = sdst[i];
        int b = d >> BSH;
        int dl = d & (GSZ - 1);
        int pos = atomicAdd(&cur[b], 1);          // LDS cursor
        pairs[pos] = (dl << 17) | s;
    }
}

// ---- passB: per-bucket counting sort by dl -> srcs (dst-sorted) + nodeptr ----
__global__ __launch_bounds__(PB) void passB_k(
    const int* __restrict__ pairs, const int* __restrict__ bbase,
    int* __restrict__ srcs, int* __restrict__ nodeptr) {
    __shared__ int hist[PB];
    __shared__ int buf[2][PB];
    __shared__ int cur[PB];
    int t = threadIdx.x, b = blockIdx.x;
    hist[t] = 0;
    __syncthreads();
    int e0 = bbase[b], e1 = bbase[b + 1];
    for (int i = e0 + t; i < e1; i += PB)
        atomicAdd(&hist[pairs[i] >> 17], 1);
    __syncthreads();
    // inclusive scan of hist[0..511] (double-buffered Hillis-Steele)
    int cb = 0;
    buf[0][t] = hist[t];
    __syncthreads();
    for (int off = 1; off < PB; off <<= 1) {
        int v = buf[cb][t];
        if (t >= off) v += buf[cb][t - off];
        buf[cb ^ 1][t] = v;
        cb ^= 1;
        __syncthreads();
    }
    int excl = buf[cb][t] - hist[t];
    cur[t] = e0 + excl;
    nodeptr[b * GSZ + t] = e0 + excl;             // nodeptr[n] exact: (n>>9)*512+(n&511)=n
    if (b == NB - 1 && t == 0) nodeptr[NB * GSZ] = e1;
    __syncthreads();
    for (int i = e0 + t; i < e1; i += PB) {
        int p = pairs[i];
        int pos = atomicAdd(&cur[p >> 17], 1);
        srcs[pos] = p & 0x1FFFF;                  // bucket-local 4B writes
    }
}

#define ACC16(P) { float4 q0 = (P)[0], q1 = (P)[1], q2 = (P)[2], q3 = (P)[3]; \
    acc[0] += q0.x;  acc[1] += q0.y;  acc[2]  += q0.z;  acc[3]  += q0.w;      \
    acc[4] += q1.x;  acc[5] += q1.y;  acc[6]  += q1.z;  acc[7]  += q1.w;      \
    acc[8] += q2.x;  acc[9] += q2.y;  acc[10] += q2.z;  acc[11] += q2.w;      \
    acc[12] += q3.x; acc[13] += q3.y; acc[14] += q3.z;  acc[15] += q3.w; }

// ---- layer 1: per-node register gather-sum (NO atomics) + MLP1 + W2a ----
__global__ __launch_bounds__(256) void gin1_k(
    const float* __restrict__ xw1, const int* __restrict__ nodeptr,
    const int* __restrict__ srcs, const float* __restrict__ b1a,
    const float* __restrict__ W1b, const float* __restrict__ b1b,
    const float* __restrict__ W2a, float* __restrict__ h1w) {
    __shared__ float sW1b[F1 * F1];
    __shared__ float sW2a[F1 * F2];
    __shared__ float sb1a[F1];
    __shared__ float sb1b[F1];
    int t = threadIdx.x;
    if (t < F1 * F1) sW1b[t] = W1b[t];
    if (t < F1 * F2) sW2a[t] = W2a[t];
    if (t < F1) { sb1a[t] = b1a[t]; sb1b[t] = b1b[t]; }
    __syncthreads();

    int n = blockIdx.x * blockDim.x + t;
    if (n >= N_NODES) return;

    float acc[F1];
#pragma unroll
    for (int k = 0; k < F1; k++) acc[k] = 0.0f;

    const float4* X = reinterpret_cast<const float4*>(xw1);
    int e = nodeptr[n];
    int end = nodeptr[n + 1];
    for (; e + 4 <= end; e += 4) {     // 16 independent loads in flight
        int s0 = srcs[e], s1 = srcs[e + 1], s2 = srcs[e + 2], s3 = srcs[e + 3];
        const float4* p0 = X + s0 * 4;
        const float4* p1 = X + s1 * 4;
        const float4* p2 = X + s2 * 4;
        const float4* p3 = X + s3 * 4;
        ACC16(p0); ACC16(p1); ACC16(p2); ACC16(p3);
    }
    for (; e < end; e++) {
        const float4* p0 = X + srcs[e] * 4;
        ACC16(p0);
    }
    {   // self term
        const float4* pn = X + n * 4;
        ACC16(pn);
    }

    float u[F1];
#pragma unroll
    for (int k = 0; k < F1; k++) u[k] = fmaxf(acc[k] + sb1a[k], 0.0f);
    float h[F1];
#pragma unroll
    for (int j = 0; j < F1; j++) {
        float s = sb1b[j];
#pragma unroll
        for (int k = 0; k < F1; k++) s += u[k] * sW1b[k * F1 + j];
        h[j] = fmaxf(s, 0.0f);          // relu∘relu = relu
    }
    float o[F2];
#pragma unroll
    for (int j = 0; j < F2; j++) {
        float s = 0.0f;
#pragma unroll
        for (int k = 0; k < F1; k++) s += h[k] * sW2a[k * F2 + j];
        o[j] = s;
    }
    float4* hp = reinterpret_cast<float4*>(h1w) + n * 2;
    hp[0] = make_float4(o[0], o[1], o[2], o[3]);
    hp[1] = make_float4(o[4], o[5], o[6], o[7]);
}

#define ACC8(P) { float4 q0 = (P)[0], q1 = (P)[1];                        \
    acc[0] += q0.x; acc[1] += q0.y; acc[2] += q0.z; acc[3] += q0.w;       \
    acc[4] += q1.x; acc[5] += q1.y; acc[6] += q1.z; acc[7] += q1.w; }

// ---- layer 2: per-node register gather-sum + MLP2 + fused mean-pool ----
__global__ __launch_bounds__(256) void gin2pool_k(
    const float* __restrict__ h1w, const int* __restrict__ nodeptr,
    const int* __restrict__ srcs, const float* __restrict__ b2a,
    const float* __restrict__ W2b, const float* __restrict__ b2b,
    const int* __restrict__ batch, float* __restrict__ gsum,
    float* __restrict__ gcnt) {
    __shared__ float sW2b[F2 * F2];
    __shared__ float sb2a[F2];
    __shared__ float sb2b[F2];
    __shared__ float ls[NGRAPH * F2];   // 512 > blockDim: MUST use strided loops
    __shared__ float lc[NGRAPH];
    int t = threadIdx.x;
    if (t < F2 * F2) sW2b[t] = W2b[t];
    if (t < F2) { sb2a[t] = b2a[t]; sb2b[t] = b2b[t]; }
    for (int i = t; i < NGRAPH * F2; i += blockDim.x) ls[i] = 0.0f;   // FIX r5 bug
    if (t < NGRAPH) lc[t] = 0.0f;
    __syncthreads();

    int n = blockIdx.x * blockDim.x + t;
    if (n < N_NODES) {
        float acc[F2];
#pragma unroll
        for (int k = 0; k < F2; k++) acc[k] = 0.0f;

        const float4* H = reinterpret_cast<const float4*>(h1w);
        int e = nodeptr[n];
        int end = nodeptr[n + 1];
        for (; e + 4 <= end; e += 4) {
            int s0 = srcs[e], s1 = srcs[e + 1], s2 = srcs[e + 2], s3 = srcs[e + 3];
            const float4* p0 = H + s0 * 2;
            const float4* p1 = H + s1 * 2;
            const float4* p2 = H + s2 * 2;
            const float4* p3 = H + s3 * 2;
            ACC8(p0); ACC8(p1); ACC8(p2); ACC8(p3);
        }
        for (; e < end; e++) {
            const float4* p0 = H + srcs[e] * 2;
            ACC8(p0);
        }
        {   // self term
            const float4* pn = H + n * 2;
            ACC8(pn);
        }

        float u[F2];
#pragma unroll
        for (int k = 0; k < F2; k++)
            u[k] = fmaxf(acc[k] + sb2a[k], 0.0f);
        float v[F2];
#pragma unroll
        for (int j = 0; j < F2; j++) {
            float s = sb2b[j];
#pragma unroll
            for (int k = 0; k < F2; k++) s += u[k] * sW2b[k * F2 + j];
            v[j] = fmaxf(s, 0.0f);
        }
        int g = batch[n];
#pragma unroll
        for (int j = 0; j < F2; j++) atomicAdd(&ls[g * F2 + j], v[j]);
        atomicAdd(&lc[g], 1.0f);
    }
    __syncthreads();
    for (int i = t; i < NGRAPH * F2; i += blockDim.x)                 // FIX r5 bug
        if (ls[i] != 0.0f) atomicAdd(&gsum[i], ls[i]);
    if (t < NGRAPH && lc[t] != 0.0f) atomicAdd(&gcnt[t], lc[t]);
}

// ---------------- final: pooled -> FC -> log_softmax ----------------
__global__ void final_k(const float* __restrict__ gsum,
                        const float* __restrict__ gcnt,
                        const float* __restrict__ Wfc, const float* __restrict__ bfc,
                        float* __restrict__ out) {
    int g = threadIdx.x;
    if (g >= NGRAPH) return;
    float cnt = fmaxf(gcnt[g], 1.0f);
    float p[F2];
#pragma unroll
    for (int f = 0; f < F2; f++) p[f] = gsum[g * F2 + f] / cnt;
    float l[NCLS];
#pragma unroll
    for (int c = 0; c < NCLS; c++) {
        float s = bfc[c];
#pragma unroll
        for (int f = 0; f < F2; f++) s += p[f] * Wfc[f * NCLS + c];
        l[c] = s;
    }
    float m = -INFINITY;
#pragma unroll
    for (int c = 0; c < NCLS; c++) m = fmaxf(m, l[c]);
    float s = 0.0f;
#pragma unroll
    for (int c = 0; c < NCLS; c++) s += expf(l[c] - m);
    float lse = m + logf(s);
#pragma unroll
    for (int c = 0; c < NCLS; c++) out[g * NCLS + c] = l[c] - lse;
}

extern "C" void kernel_launch(void* const* d_in, const int* in_sizes, int n_in,
                              void* d_out, int out_size, void* d_ws, size_t ws_size,
                              hipStream_t stream) {
    const float* x    = (const float*)d_in[0];
    const int*   ei   = (const int*)d_in[1];   // [2, N_EDGES]
    const int*   batch= (const int*)d_in[2];   // [N_NODES], sorted
    const float* W1a  = (const float*)d_in[3];
    const float* b1a  = (const float*)d_in[4];
    const float* W1b  = (const float*)d_in[5];
    const float* b1b  = (const float*)d_in[6];
    const float* W2a  = (const float*)d_in[7];
    const float* b2a  = (const float*)d_in[8];
    const float* W2b  = (const float*)d_in[9];
    const float* b2b  = (const float*)d_in[10];
    const float* Wfc  = (const float*)d_in[11];
    const float* bfc  = (const float*)d_in[12];
    float* out = (float*)d_out;

    // workspace layout (4-byte units), ~22.9 MB total
    float* ws      = (float*)d_ws;
    float* xw1     = ws;                                   // N_NODES*16 (16B aligned)
    float* h1w     = xw1 + (size_t)N_NODES * F1;           // N_NODES*8
    int*   pairs   = (int*)(h1w + (size_t)N_NODES * F2);   // N_EDGES
    int*   srcs    = pairs + N_EDGES;                      // N_EDGES (dst-sorted)
    int*   nodeptr = srcs + N_EDGES;                       // NB*GSZ+1 = 100353
    int*   bbase   = nodeptr + NB * GSZ + 4;               // 257
    int*   gcursor = bbase + 260;                          // 256
    int*   bhist   = gcursor + 256;                        // 256     (memset)
    float* gsum    = (float*)(bhist + 256);                // NGRAPH*F2 (memset)
    float* gcnt    = gsum + NGRAPH * F2;                   // NGRAPH  (memset)

    // one tiny memset: bhist + gsum + gcnt adjacent
    hipMemsetAsync(bhist, 0, (256 + NGRAPH * F2 + NGRAPH) * sizeof(int), stream);

    xform_k<<<(N_NODES + 255) / 256, 256, 0, stream>>>(x, W1a, xw1);
    bhist_k<<<NCH, 256, 0, stream>>>(ei, bhist);
    bscan_k<<<1, 256, 0, stream>>>(bhist, bbase, gcursor);
    passA_k<<<NCH, 256, 0, stream>>>(ei, gcursor, pairs);
    passB_k<<<NB, PB, 0, stream>>>(pairs, bbase, srcs, nodeptr);
    gin1_k<<<(N_NODES + 255) / 256, 256, 0, stream>>>(xw1, nodeptr, srcs,
                                                      b1a, W1b, b1b, W2a, h1w);
    gin2pool_k<<<(N_NODES + 255) / 256, 256, 0, stream>>>(h1w, nodeptr, srcs,
                                                          b2a, W2b, b2b, batch,
                                                          gsum, gcnt);
    final_k<<<1, 64, 0, stream>>>(gsum, gcnt, Wfc, bfc, out);
}